// Round 17
// baseline (209.504 us; speedup 1.0000x reference)
//
#include <hip/hip_runtime.h>
#include <hip/hip_bf16.h>
#include <math.h>

#define N_TOT   16384
#define M_EV    4096
#define IN_DIM  128
#define SPACE_D 4
#define PROP_D  64
#define K_NN    32
#define CAND_CAP 128            // survivor slots per row (2/lane)
#define MARGIN  0.04f           // covers f16 approx error near threshold (>= 2*err)

typedef _Float16 h2 __attribute__((ext_vector_type(2)));
typedef __attribute__((ext_vector_type(8))) _Float16 h16x8;
typedef __attribute__((ext_vector_type(4))) float f32x4;
typedef unsigned long long u64;

__device__ __forceinline__ h2 pkmin(h2 a, h2 b) {
#if __has_builtin(__builtin_elementwise_min)
  return __builtin_elementwise_min(a, b);
#else
  h2 r; r.x = (a.x < b.x) ? a.x : b.x; r.y = (a.y < b.y) ? a.y : b.y; return r;
#endif
}

__device__ __forceinline__ h2 pkrtz(float a, float b) {
  return __builtin_bit_cast(h2, __builtin_amdgcn_cvt_pkrtz(a, b));
}

// per-lane count of set bits of mk strictly below this lane
__device__ __forceinline__ int mbcnt64(u64 mk) {
  return (int)__builtin_amdgcn_mbcnt_hi((unsigned)(mk >> 32),
           __builtin_amdgcn_mbcnt_lo((unsigned)mk, 0u));
}

// ---------------------------------------------------------------------------
// Kernel 1: space = x @ Ws + bs (exact f32, all 64 lanes);
//           prop  = x @ Wp + bp via mfma_f32_16x16x32_f16 (f32 accumulate).
// (R13 version — passed absmax 0.0156.)
// ---------------------------------------------------------------------------
__global__ __launch_bounds__(256) void linear_kernel(
    const float* __restrict__ x,
    const float* __restrict__ Ws, const float* __restrict__ bs,
    const float* __restrict__ Wp, const float* __restrict__ bp,
    float* __restrict__ space, float* __restrict__ prop)
{
  const int lane = threadIdx.x & 63;
  const int wid  = threadIdx.x >> 6;
  const int r0w  = ((int)blockIdx.x * 4 + wid) * 16;   // wave's 16-row tile

  __shared__ _Float16 s_wp[PROP_D][IN_DIM + 8];        // transposed Wp, padded

  // stage Wp (f32 [k][c]) -> s_wp[c][k] f16
  for (int e = (int)threadIdx.x; e < IN_DIM * PROP_D; e += 256) {
    const int k = e >> 6, c = e & 63;
    s_wp[c][k] = (_Float16)Wp[e];
  }
  __syncthreads();

  // ---- space: exact f32, lane = (row, col) = (lane>>2, lane&3) ----
  {
    const int r = lane >> 2, c = lane & 3;
    const float4* __restrict__ xq = (const float4*)(x + (size_t)(r0w + r) * IN_DIM);
    float a = bs[c];
    #pragma unroll
    for (int i = 0; i < 32; ++i) {
      const float4 v = xq[i];
      a = fmaf(v.x, Ws[(i * 4 + 0) * SPACE_D + c], a);
      a = fmaf(v.y, Ws[(i * 4 + 1) * SPACE_D + c], a);
      a = fmaf(v.z, Ws[(i * 4 + 2) * SPACE_D + c], a);
      a = fmaf(v.w, Ws[(i * 4 + 3) * SPACE_D + c], a);
    }
    space[(size_t)(r0w + r) * SPACE_D + c] = a;
  }

  // ---- prop: MFMA, 4 k-steps x 4 col-tiles ----
  f32x4 acc0 = {0.f, 0.f, 0.f, 0.f};
  f32x4 acc1 = {0.f, 0.f, 0.f, 0.f};
  f32x4 acc2 = {0.f, 0.f, 0.f, 0.f};
  f32x4 acc3 = {0.f, 0.f, 0.f, 0.f};

  const int arow = lane & 15;
  const int kgrp = (lane >> 4) * 8;                    // k-group base (8 elems)

  #pragma unroll
  for (int kk = 0; kk < 4; ++kk) {
    const float4* xa = (const float4*)(x + (size_t)(r0w + arow) * IN_DIM
                                         + kk * 32 + kgrp);
    const float4 a0 = xa[0], a1 = xa[1];
    uint4 au;
    au.x = __builtin_bit_cast(unsigned, pkrtz(a0.x, a0.y));
    au.y = __builtin_bit_cast(unsigned, pkrtz(a0.z, a0.w));
    au.z = __builtin_bit_cast(unsigned, pkrtz(a1.x, a1.y));
    au.w = __builtin_bit_cast(unsigned, pkrtz(a1.z, a1.w));
    const h16x8 afrag = __builtin_bit_cast(h16x8, au);

    const int kb = kk * 32 + kgrp;
    const h16x8 b0 = *(const h16x8*)&s_wp[ 0 + arow][kb];
    const h16x8 b1 = *(const h16x8*)&s_wp[16 + arow][kb];
    const h16x8 b2 = *(const h16x8*)&s_wp[32 + arow][kb];
    const h16x8 b3 = *(const h16x8*)&s_wp[48 + arow][kb];
    acc0 = __builtin_amdgcn_mfma_f32_16x16x32_f16(afrag, b0, acc0, 0, 0, 0);
    acc1 = __builtin_amdgcn_mfma_f32_16x16x32_f16(afrag, b1, acc1, 0, 0, 0);
    acc2 = __builtin_amdgcn_mfma_f32_16x16x32_f16(afrag, b2, acc2, 0, 0, 0);
    acc3 = __builtin_amdgcn_mfma_f32_16x16x32_f16(afrag, b3, acc3, 0, 0, 0);
  }

  {
    const int rbase = (lane >> 4) * 4;
    const float bp0 = bp[ 0 + arow];
    const float bp1 = bp[16 + arow];
    const float bp2 = bp[32 + arow];
    const float bp3 = bp[48 + arow];
    #pragma unroll
    for (int j = 0; j < 4; ++j) {
      float* pr = prop + (size_t)(r0w + rbase + j) * PROP_D;
      pr[ 0 + arow] = acc0[j] + bp0;
      pr[16 + arow] = acc1[j] + bp1;
      pr[32 + arow] = acc2[j] + bp2;
      pr[48 + arow] = acc3[j] + bp3;
    }
  }
}

// ---------------------------------------------------------------------------
// Kernel 2: per-row exact KNN (K=32 of 4096) + weighted aggregation.
// Phase-split variant of the R15 structure (no asm, no clobbers):
//  A1: t=0..15 -> 16 pd regs + packed lane-min.
//  Tub: 32nd of the 128 phase-1 partition mins (valid upper bound: each of
//       the 32 partitions with min <= Tub contributes >= 1 candidate).
//  A2: t=16..31 fused compute+compare+append (each candidate read & computed
//      exactly ONCE).
//  B1: t=0..15 compares from the held registers (compiler may remat -> then
//      this equals R9/R15, neutral).
// Tail unchanged: exact f32 refine + f32-bit bisect + stable tie select.
// ---------------------------------------------------------------------------
__global__ __launch_bounds__(512, 3) void knn_kernel(
    const float4* __restrict__ space,   // [N_TOT] f32 coords
    const float*  __restrict__ prop,    // [N_TOT * PROP_D]
    float*        __restrict__ out)     // [N_TOT * 2*PROP_D]
{
  const int lane = threadIdx.x & 63;
  const int wid  = threadIdx.x >> 6;              // 0..7
  const int row  = (int)blockIdx.x * 8 + wid;     // 1 wave = 1 row
  const int m0   = row & ~(M_EV - 1);
  const int mloc = row & (M_EV - 1);

  __shared__ uint4 s_pk[M_EV / 2];                // 32 KB pair-packed f16
  __shared__ int   s_ci[8][CAND_CAP];             // 4 KB survivor indices
  __shared__ uint2 s_w[8][K_NN];                  // 2 KB winners {idx, wbits}
  __shared__ int   s_cnt[8];

  // stage: pack pairs (i, i+2048) as f16x2 per dim
  {
    const float4* src = space + m0;
    #pragma unroll
    for (int it = 0; it < 4; ++it) {
      const int i = (int)threadIdx.x + it * 512;
      const float4 a = src[i];
      const float4 b = src[i + 2048];
      s_pk[i] = make_uint4(
        __builtin_bit_cast(unsigned, pkrtz(a.x, b.x)),
        __builtin_bit_cast(unsigned, pkrtz(a.y, b.y)),
        __builtin_bit_cast(unsigned, pkrtz(a.z, b.z)),
        __builtin_bit_cast(unsigned, pkrtz(a.w, b.w)));
    }
  }
  if (lane == 0) s_cnt[wid] = 0;
  __syncthreads();

  // query coords: exact f32 (for refine) + duplicated f16 packs
  const float4 qf = space[m0 + mloc];
  const h2 qx = pkrtz(qf.x, qf.x), qy = pkrtz(qf.y, qf.y);
  const h2 qz = pkrtz(qf.z, qf.z), qw = pkrtz(qf.w, qf.w);

  // --- phase A1: t=0..15 -> distances in 16 regs + running packed min ---
  unsigned pd[16];
  h2 mn; mn.x = (_Float16)65504.f; mn.y = (_Float16)65504.f;
  #pragma unroll
  for (int t = 0; t < 16; ++t) {
    const uint4 u = s_pk[lane + (t << 6)];
    const h2 dx = qx - __builtin_bit_cast(h2, u.x);
    const h2 dy = qy - __builtin_bit_cast(h2, u.y);
    const h2 dz = qz - __builtin_bit_cast(h2, u.z);
    const h2 dw = qw - __builtin_bit_cast(h2, u.w);
    h2 s = dx * dx;
    s = dy * dy + s;
    s = dz * dz + s;
    s = dw * dw + s;
    pd[t] = __builtin_bit_cast(unsigned, s);
    mn = pkmin(mn, s);
  }

  // --- Tub: 32nd smallest of the 128 phase-1 partition mins (f16 codes) ---
  const unsigned mnbits = __builtin_bit_cast(unsigned, mn);
  const unsigned c0 = mnbits & 0xFFFFu, c1 = mnbits >> 16;
  unsigned blo = 0u, bhi = 0x7C00u;
  while (blo < bhi) {
    const unsigned mid = (blo + bhi) >> 1;
    const int c = (int)__popcll(__ballot(c0 <= mid)) +
                  (int)__popcll(__ballot(c1 <= mid));
    if (c >= K_NN) { bhi = mid; if (c == K_NN) break; }
    else blo = mid + 1;
  }
  const float T = (float)__builtin_bit_cast(_Float16, (unsigned short)bhi) + MARGIN;
  const h2 Th = pkrtz(T, T);                      // RTZ error << MARGIN

  // --- phase A2: t=16..31 fused compute + compare + append (read once) ---
  #pragma unroll
  for (int t = 16; t < 32; ++t) {
    const uint4 u = s_pk[lane + (t << 6)];
    const h2 dx = qx - __builtin_bit_cast(h2, u.x);
    const h2 dy = qy - __builtin_bit_cast(h2, u.y);
    const h2 dz = qz - __builtin_bit_cast(h2, u.z);
    const h2 dw = qw - __builtin_bit_cast(h2, u.w);
    h2 s = dx * dx;
    s = dy * dy + s;
    s = dz * dz + s;
    s = dw * dw + s;
    if (s.x <= Th.x) {
      const int pos = atomicAdd(&s_cnt[wid], 1);
      if (pos < CAND_CAP) s_ci[wid][pos] = (t << 6) + lane;
    }
    if (s.y <= Th.y) {
      const int pos = atomicAdd(&s_cnt[wid], 1);
      if (pos < CAND_CAP) s_ci[wid][pos] = (t << 6) + lane + 2048;
    }
  }

  // --- phase B1: t=0..15 compares from held registers + append ---
  #pragma unroll
  for (int t = 0; t < 16; ++t) {
    const h2 s = __builtin_bit_cast(h2, pd[t]);
    if (s.x <= Th.x) {
      const int pos = atomicAdd(&s_cnt[wid], 1);
      if (pos < CAND_CAP) s_ci[wid][pos] = (t << 6) + lane;
    }
    if (s.y <= Th.y) {
      const int pos = atomicAdd(&s_cnt[wid], 1);
      if (pos < CAND_CAP) s_ci[wid][pos] = (t << 6) + lane + 2048;
    }
  }
  int C = s_cnt[wid];

  if (C > CAND_CAP) {
    // --- cold exact fallback: bisect exact f32 d from global, fill top-32 ---
    const float4* __restrict__ ev = space + m0;
    unsigned lo = 0u, hi = __float_as_uint(T);
    while (lo < hi) {
      const unsigned mid = (lo + hi) >> 1;
      const float fm = __uint_as_float(mid);
      int c = 0;
      #pragma unroll 1
      for (int t = 0; t < 64; ++t) {
        const float4 cc = ev[lane + (t << 6)];
        const float dx = qf.x - cc.x, dy = qf.y - cc.y;
        const float dz = qf.z - cc.z, dw = qf.w - cc.w;
        const float dd = fmaf(dx, dx, fmaf(dy, dy, fmaf(dz, dz, dw * dw)));
        c += (int)__popcll(__ballot(dd <= fm));
      }
      if (c >= K_NN) { hi = mid; if (c == K_NN) break; }
      else lo = mid + 1;
    }
    const float Tf = __uint_as_float(hi);
    int cnt = 0;
    #pragma unroll 1
    for (int pass = 0; pass < 2; ++pass) {        // 0: strict-less, 1: equal
      #pragma unroll 1
      for (int t = 0; t < 64; ++t) {
        const float4 cc = ev[lane + (t << 6)];
        const float dx = qf.x - cc.x, dy = qf.y - cc.y;
        const float dz = qf.z - cc.z, dw = qf.w - cc.w;
        const float dd = fmaf(dx, dx, fmaf(dy, dy, fmaf(dz, dz, dw * dw)));
        const bool p = pass ? (dd == Tf) : (dd < Tf);
        const u64 mk = __ballot(p);
        if (p) {
          const int pos = cnt + mbcnt64(mk);
          if (pos < K_NN) s_ci[wid][pos] = (t << 6) + lane;
        }
        cnt += (int)__popcll(mk);
      }
      if (cnt >= K_NN) break;
    }
    C = K_NN;
  }

  // --- refine: exact f32 distances for <=2 survivors/lane (global, L2) ---
  const bool h0 = (lane < C), h1 = (64 + lane < C);
  const int i0 = h0 ? s_ci[wid][lane]      : 0;
  const int i1 = h1 ? s_ci[wid][64 + lane] : 0;
  float v0 = INFINITY, v1 = INFINITY;
  if (h0) {
    const float4 cc = space[m0 + i0];
    const float dx = qf.x - cc.x, dy = qf.y - cc.y;
    const float dz = qf.z - cc.z, dw = qf.w - cc.w;
    v0 = fmaf(dx, dx, fmaf(dy, dy, fmaf(dz, dz, dw * dw)));
  }
  if (h1) {
    const float4 cc = space[m0 + i1];
    const float dx = qf.x - cc.x, dy = qf.y - cc.y;
    const float dz = qf.z - cc.z, dw = qf.w - cc.w;
    v1 = fmaf(dx, dx, fmaf(dy, dy, fmaf(dz, dz, dw * dw)));
  }

  // --- tail: f32-bits bisect (early exit at c==32) on <=2 values/lane ---
  unsigned lo = 0u, hi = __float_as_uint(T);
  while (lo < hi) {
    const unsigned mid = (lo + hi) >> 1;
    const float fm = __uint_as_float(mid);
    const int c = (int)__popcll(__ballot(v0 <= fm)) +
                  (int)__popcll(__ballot(v1 <= fm));
    if (c >= K_NN) { hi = mid; if (c == K_NN) break; }
    else lo = mid + 1;
  }
  const float T2 = __uint_as_float(hi);

  // stable selection: strict-less, then lowest-position equals (JAX order;
  // exact f32 ties across distinct candidates have ~0 probability here)
  const u64 mkE0 = __ballot(v0 == T2);
  const u64 mkE1 = __ballot(v1 == T2);
  const int L = (int)__popcll(__ballot(v0 < T2)) +
                (int)__popcll(__ballot(v1 < T2));
  const int e = K_NN - L;
  const int nE0 = (int)__popcll(mkE0);
  const bool sel0 = (v0 < T2) || ((v0 == T2) && (mbcnt64(mkE0) < e));
  const bool sel1 = (v1 < T2) || ((v1 == T2) && (nE0 + mbcnt64(mkE1) < e));

  const float w0 = __expf(-10.f * v0);
  const float w1 = __expf(-10.f * v1);

  {
    const u64 mkS0 = __ballot(sel0);
    if (sel0) {
      const int pos = mbcnt64(mkS0);
      s_w[wid][pos] = make_uint2((unsigned)i0, __float_as_uint(w0));
    }
    const int b0 = (int)__popcll(mkS0);
    const u64 mkS1 = __ballot(sel1);
    if (sel1) {
      const int pos = b0 + mbcnt64(mkS1);
      s_w[wid][pos] = make_uint2((unsigned)i1, __float_as_uint(w1));
    }
  }

  // --- aggregation: lane = feature, 32 winners ---
  float accm = 0.f;
  float accx = -INFINITY;
  const float* __restrict__ pb = prop + ((size_t)m0 << 6) + lane;
  #pragma unroll 8
  for (int n = 0; n < K_NN; ++n) {
    const uint2 wn = s_w[wid][n];                 // uniform LDS broadcast
    const float w = __uint_as_float(wn.y);
    const float v = pb[(size_t)wn.x << 6];        // coalesced 256B, L2-hot
    const float wv = w * v;
    accm += wv;
    accx = fmaxf(accx, wv);
  }
  out[(size_t)row * 128 + lane]      = accm * (1.f / K_NN);
  out[(size_t)row * 128 + 64 + lane] = accx;
}

// ---------------------------------------------------------------------------
extern "C" void kernel_launch(void* const* d_in, const int* in_sizes, int n_in,
                              void* d_out, int out_size, void* d_ws, size_t ws_size,
                              hipStream_t stream) {
  const float* x  = (const float*)d_in[0];
  const float* Ws = (const float*)d_in[1];
  const float* bs = (const float*)d_in[2];
  const float* Wp = (const float*)d_in[3];
  const float* bp = (const float*)d_in[4];
  float* out = (float*)d_out;

  // workspace layout: prop [N,64] f32 (4 MB) | space [N,4] f32 (256 KB)
  float* prop  = (float*)d_ws;
  float* space = (float*)((char*)d_ws + (size_t)N_TOT * PROP_D * sizeof(float));

  linear_kernel<<<N_TOT / 64, 256, 0, stream>>>(x, Ws, bs, Wp, bp, space, prop);
  knn_kernel<<<N_TOT / 8, 512, 0, stream>>>((const float4*)space, prop, out);
}

// Round 18
// 52.280 us; speedup vs baseline: 4.0073x; 4.0073x over previous
//
#include <hip/hip_runtime.h>
#include <hip/hip_bf16.h>
#include <math.h>

#define N_TOT   16384
#define M_EV    4096
#define IN_DIM  128
#define SPACE_D 4
#define PROP_D  64
#define K_NN    32
#define CAND_CAP 128            // survivor slots per row (2/lane)
#define MARGIN  0.04f           // covers f16 approx error near threshold (>= 2*err)

typedef _Float16 h2 __attribute__((ext_vector_type(2)));
typedef __attribute__((ext_vector_type(8))) _Float16 h16x8;
typedef __attribute__((ext_vector_type(4))) float f32x4;
typedef unsigned long long u64;

__device__ __forceinline__ h2 pkmin(h2 a, h2 b) {
#if __has_builtin(__builtin_elementwise_min)
  return __builtin_elementwise_min(a, b);
#else
  h2 r; r.x = (a.x < b.x) ? a.x : b.x; r.y = (a.y < b.y) ? a.y : b.y; return r;
#endif
}

__device__ __forceinline__ h2 pkrtz(float a, float b) {
  return __builtin_bit_cast(h2, __builtin_amdgcn_cvt_pkrtz(a, b));
}

// per-lane count of set bits of mk strictly below this lane
__device__ __forceinline__ int mbcnt64(u64 mk) {
  return (int)__builtin_amdgcn_mbcnt_hi((unsigned)(mk >> 32),
           __builtin_amdgcn_mbcnt_lo((unsigned)mk, 0u));
}

// ---------------------------------------------------------------------------
// Kernel 1: space = x @ Ws + bs (exact f32, all 64 lanes);
//           prop  = x @ Wp + bp via mfma_f32_16x16x32_f16 (f32 accumulate).
// (R13 version — passed absmax 0.0156.)
// ---------------------------------------------------------------------------
__global__ __launch_bounds__(256) void linear_kernel(
    const float* __restrict__ x,
    const float* __restrict__ Ws, const float* __restrict__ bs,
    const float* __restrict__ Wp, const float* __restrict__ bp,
    float* __restrict__ space, float* __restrict__ prop)
{
  const int lane = threadIdx.x & 63;
  const int wid  = threadIdx.x >> 6;
  const int r0w  = ((int)blockIdx.x * 4 + wid) * 16;   // wave's 16-row tile

  __shared__ _Float16 s_wp[PROP_D][IN_DIM + 8];        // transposed Wp, padded

  // stage Wp (f32 [k][c]) -> s_wp[c][k] f16
  for (int e = (int)threadIdx.x; e < IN_DIM * PROP_D; e += 256) {
    const int k = e >> 6, c = e & 63;
    s_wp[c][k] = (_Float16)Wp[e];
  }
  __syncthreads();

  // ---- space: exact f32, lane = (row, col) = (lane>>2, lane&3) ----
  {
    const int r = lane >> 2, c = lane & 3;
    const float4* __restrict__ xq = (const float4*)(x + (size_t)(r0w + r) * IN_DIM);
    float a = bs[c];
    #pragma unroll
    for (int i = 0; i < 32; ++i) {
      const float4 v = xq[i];
      a = fmaf(v.x, Ws[(i * 4 + 0) * SPACE_D + c], a);
      a = fmaf(v.y, Ws[(i * 4 + 1) * SPACE_D + c], a);
      a = fmaf(v.z, Ws[(i * 4 + 2) * SPACE_D + c], a);
      a = fmaf(v.w, Ws[(i * 4 + 3) * SPACE_D + c], a);
    }
    space[(size_t)(r0w + r) * SPACE_D + c] = a;
  }

  // ---- prop: MFMA, 4 k-steps x 4 col-tiles ----
  f32x4 acc0 = {0.f, 0.f, 0.f, 0.f};
  f32x4 acc1 = {0.f, 0.f, 0.f, 0.f};
  f32x4 acc2 = {0.f, 0.f, 0.f, 0.f};
  f32x4 acc3 = {0.f, 0.f, 0.f, 0.f};

  const int arow = lane & 15;
  const int kgrp = (lane >> 4) * 8;                    // k-group base (8 elems)

  #pragma unroll
  for (int kk = 0; kk < 4; ++kk) {
    const float4* xa = (const float4*)(x + (size_t)(r0w + arow) * IN_DIM
                                         + kk * 32 + kgrp);
    const float4 a0 = xa[0], a1 = xa[1];
    uint4 au;
    au.x = __builtin_bit_cast(unsigned, pkrtz(a0.x, a0.y));
    au.y = __builtin_bit_cast(unsigned, pkrtz(a0.z, a0.w));
    au.z = __builtin_bit_cast(unsigned, pkrtz(a1.x, a1.y));
    au.w = __builtin_bit_cast(unsigned, pkrtz(a1.z, a1.w));
    const h16x8 afrag = __builtin_bit_cast(h16x8, au);

    const int kb = kk * 32 + kgrp;
    const h16x8 b0 = *(const h16x8*)&s_wp[ 0 + arow][kb];
    const h16x8 b1 = *(const h16x8*)&s_wp[16 + arow][kb];
    const h16x8 b2 = *(const h16x8*)&s_wp[32 + arow][kb];
    const h16x8 b3 = *(const h16x8*)&s_wp[48 + arow][kb];
    acc0 = __builtin_amdgcn_mfma_f32_16x16x32_f16(afrag, b0, acc0, 0, 0, 0);
    acc1 = __builtin_amdgcn_mfma_f32_16x16x32_f16(afrag, b1, acc1, 0, 0, 0);
    acc2 = __builtin_amdgcn_mfma_f32_16x16x32_f16(afrag, b2, acc2, 0, 0, 0);
    acc3 = __builtin_amdgcn_mfma_f32_16x16x32_f16(afrag, b3, acc3, 0, 0, 0);
  }

  {
    const int rbase = (lane >> 4) * 4;
    const float bp0 = bp[ 0 + arow];
    const float bp1 = bp[16 + arow];
    const float bp2 = bp[32 + arow];
    const float bp3 = bp[48 + arow];
    #pragma unroll
    for (int j = 0; j < 4; ++j) {
      float* pr = prop + (size_t)(r0w + rbase + j) * PROP_D;
      pr[ 0 + arow] = acc0[j] + bp0;
      pr[16 + arow] = acc1[j] + bp1;
      pr[32 + arow] = acc2[j] + bp2;
      pr[48 + arow] = acc3[j] + bp3;
    }
  }
}

// ---------------------------------------------------------------------------
// Kernel 2: per-row exact KNN (K=32 of 4096) + weighted aggregation.
// R15 structure (measured best: knn ~41.3 us, total 52.4 us).
// 512 thr = 8 waves = 8 rows; slab pair-packed f16 in LDS (32 KB).
// Pass A: 4096 approx distances (packed f16) + running packed lane-min.
// Tub: 15-iter integer bisect on f16 code space of the 128 partition mins.
// Pass B: compares + LDS-atomic append (compiler remat accepted — all
// register-residency fights measured <= 0 across R9/R11/R12/R14/R17).
// Refine: exact f32 from global for <=2 survivors/lane; f32-bit bisect +
// stable lowest-index tie select (exact JAX semantics). Cold exact fallback.
// ---------------------------------------------------------------------------
__global__ __launch_bounds__(512, 3) void knn_kernel(
    const float4* __restrict__ space,   // [N_TOT] f32 coords
    const float*  __restrict__ prop,    // [N_TOT * PROP_D]
    float*        __restrict__ out)     // [N_TOT * 2*PROP_D]
{
  const int lane = threadIdx.x & 63;
  const int wid  = threadIdx.x >> 6;              // 0..7
  const int row  = (int)blockIdx.x * 8 + wid;     // 1 wave = 1 row
  const int m0   = row & ~(M_EV - 1);
  const int mloc = row & (M_EV - 1);

  __shared__ uint4 s_pk[M_EV / 2];                // 32 KB pair-packed f16
  __shared__ int   s_ci[8][CAND_CAP];             // 4 KB survivor indices
  __shared__ uint2 s_w[8][K_NN];                  // 2 KB winners {idx, wbits}
  __shared__ int   s_cnt[8];

  // stage: pack pairs (i, i+2048) as f16x2 per dim
  {
    const float4* src = space + m0;
    #pragma unroll
    for (int it = 0; it < 4; ++it) {
      const int i = (int)threadIdx.x + it * 512;
      const float4 a = src[i];
      const float4 b = src[i + 2048];
      s_pk[i] = make_uint4(
        __builtin_bit_cast(unsigned, pkrtz(a.x, b.x)),
        __builtin_bit_cast(unsigned, pkrtz(a.y, b.y)),
        __builtin_bit_cast(unsigned, pkrtz(a.z, b.z)),
        __builtin_bit_cast(unsigned, pkrtz(a.w, b.w)));
    }
  }
  if (lane == 0) s_cnt[wid] = 0;
  __syncthreads();

  // query coords: exact f32 (for refine) + duplicated f16 packs
  const float4 qf = space[m0 + mloc];
  const h2 qx = pkrtz(qf.x, qf.x), qy = pkrtz(qf.y, qf.y);
  const h2 qz = pkrtz(qf.z, qf.z), qw = pkrtz(qf.w, qf.w);

  // --- pass A: packed distances -> 32 regs + running packed min ---
  unsigned pd[32];
  h2 mn; mn.x = (_Float16)65504.f; mn.y = (_Float16)65504.f;
  #pragma unroll
  for (int t = 0; t < 32; ++t) {
    const uint4 u = s_pk[lane + (t << 6)];
    const h2 dx = qx - __builtin_bit_cast(h2, u.x);
    const h2 dy = qy - __builtin_bit_cast(h2, u.y);
    const h2 dz = qz - __builtin_bit_cast(h2, u.z);
    const h2 dw = qw - __builtin_bit_cast(h2, u.w);
    h2 s = dx * dx;
    s = dy * dy + s;
    s = dz * dz + s;
    s = dw * dw + s;
    pd[t] = __builtin_bit_cast(unsigned, s);
    mn = pkmin(mn, s);
  }

  // --- Tub: 32nd smallest of 128 partition mins, bisect on f16 CODE space ---
  const unsigned mnbits = __builtin_bit_cast(unsigned, mn);
  const unsigned c0 = mnbits & 0xFFFFu, c1 = mnbits >> 16;
  unsigned blo = 0u, bhi = 0x7C00u;
  while (blo < bhi) {
    const unsigned mid = (blo + bhi) >> 1;
    const int c = (int)__popcll(__ballot(c0 <= mid)) +
                  (int)__popcll(__ballot(c1 <= mid));
    if (c >= K_NN) { bhi = mid; if (c == K_NN) break; }
    else blo = mid + 1;
  }
  const float T = (float)__builtin_bit_cast(_Float16, (unsigned short)bhi) + MARGIN;
  const h2 Th = pkrtz(T, T);                      // RTZ error << MARGIN

  // --- pass B: compares + LDS-atomic append of indices ---
  #pragma unroll
  for (int t = 0; t < 32; ++t) {
    const h2 s = __builtin_bit_cast(h2, pd[t]);
    if (s.x <= Th.x) {
      const int pos = atomicAdd(&s_cnt[wid], 1);
      if (pos < CAND_CAP) s_ci[wid][pos] = (t << 6) + lane;
    }
    if (s.y <= Th.y) {
      const int pos = atomicAdd(&s_cnt[wid], 1);
      if (pos < CAND_CAP) s_ci[wid][pos] = (t << 6) + lane + 2048;
    }
  }
  int C = s_cnt[wid];

  if (C > CAND_CAP) {
    // --- cold exact fallback: bisect exact f32 d from global, fill top-32 ---
    const float4* __restrict__ ev = space + m0;
    unsigned lo = 0u, hi = __float_as_uint(T);
    while (lo < hi) {
      const unsigned mid = (lo + hi) >> 1;
      const float fm = __uint_as_float(mid);
      int c = 0;
      #pragma unroll 1
      for (int t = 0; t < 64; ++t) {
        const float4 cc = ev[lane + (t << 6)];
        const float dx = qf.x - cc.x, dy = qf.y - cc.y;
        const float dz = qf.z - cc.z, dw = qf.w - cc.w;
        const float dd = fmaf(dx, dx, fmaf(dy, dy, fmaf(dz, dz, dw * dw)));
        c += (int)__popcll(__ballot(dd <= fm));
      }
      if (c >= K_NN) { hi = mid; if (c == K_NN) break; }
      else lo = mid + 1;
    }
    const float Tf = __uint_as_float(hi);
    int cnt = 0;
    #pragma unroll 1
    for (int pass = 0; pass < 2; ++pass) {        // 0: strict-less, 1: equal
      #pragma unroll 1
      for (int t = 0; t < 64; ++t) {
        const float4 cc = ev[lane + (t << 6)];
        const float dx = qf.x - cc.x, dy = qf.y - cc.y;
        const float dz = qf.z - cc.z, dw = qf.w - cc.w;
        const float dd = fmaf(dx, dx, fmaf(dy, dy, fmaf(dz, dz, dw * dw)));
        const bool p = pass ? (dd == Tf) : (dd < Tf);
        const u64 mk = __ballot(p);
        if (p) {
          const int pos = cnt + mbcnt64(mk);
          if (pos < K_NN) s_ci[wid][pos] = (t << 6) + lane;
        }
        cnt += (int)__popcll(mk);
      }
      if (cnt >= K_NN) break;
    }
    C = K_NN;
  }

  // --- refine: exact f32 distances for <=2 survivors/lane (global, L2) ---
  const bool h0 = (lane < C), h1 = (64 + lane < C);
  const int i0 = h0 ? s_ci[wid][lane]      : 0;
  const int i1 = h1 ? s_ci[wid][64 + lane] : 0;
  float v0 = INFINITY, v1 = INFINITY;
  if (h0) {
    const float4 cc = space[m0 + i0];
    const float dx = qf.x - cc.x, dy = qf.y - cc.y;
    const float dz = qf.z - cc.z, dw = qf.w - cc.w;
    v0 = fmaf(dx, dx, fmaf(dy, dy, fmaf(dz, dz, dw * dw)));
  }
  if (h1) {
    const float4 cc = space[m0 + i1];
    const float dx = qf.x - cc.x, dy = qf.y - cc.y;
    const float dz = qf.z - cc.z, dw = qf.w - cc.w;
    v1 = fmaf(dx, dx, fmaf(dy, dy, fmaf(dz, dz, dw * dw)));
  }

  // --- tail: f32-bits bisect (early exit at c==32) on <=2 values/lane ---
  unsigned lo = 0u, hi = __float_as_uint(T);
  while (lo < hi) {
    const unsigned mid = (lo + hi) >> 1;
    const float fm = __uint_as_float(mid);
    const int c = (int)__popcll(__ballot(v0 <= fm)) +
                  (int)__popcll(__ballot(v1 <= fm));
    if (c >= K_NN) { hi = mid; if (c == K_NN) break; }
    else lo = mid + 1;
  }
  const float T2 = __uint_as_float(hi);

  // stable selection: strict-less, then lowest-position equals (JAX order)
  const u64 mkE0 = __ballot(v0 == T2);
  const u64 mkE1 = __ballot(v1 == T2);
  const int L = (int)__popcll(__ballot(v0 < T2)) +
                (int)__popcll(__ballot(v1 < T2));
  const int e = K_NN - L;
  const int nE0 = (int)__popcll(mkE0);
  const bool sel0 = (v0 < T2) || ((v0 == T2) && (mbcnt64(mkE0) < e));
  const bool sel1 = (v1 < T2) || ((v1 == T2) && (nE0 + mbcnt64(mkE1) < e));

  const float w0 = __expf(-10.f * v0);
  const float w1 = __expf(-10.f * v1);

  {
    const u64 mkS0 = __ballot(sel0);
    if (sel0) {
      const int pos = mbcnt64(mkS0);
      s_w[wid][pos] = make_uint2((unsigned)i0, __float_as_uint(w0));
    }
    const int b0 = (int)__popcll(mkS0);
    const u64 mkS1 = __ballot(sel1);
    if (sel1) {
      const int pos = b0 + mbcnt64(mkS1);
      s_w[wid][pos] = make_uint2((unsigned)i1, __float_as_uint(w1));
    }
  }

  // --- aggregation: lane = feature, 32 winners ---
  float accm = 0.f;
  float accx = -INFINITY;
  const float* __restrict__ pb = prop + ((size_t)m0 << 6) + lane;
  #pragma unroll 8
  for (int n = 0; n < K_NN; ++n) {
    const uint2 wn = s_w[wid][n];                 // uniform LDS broadcast
    const float w = __uint_as_float(wn.y);
    const float v = pb[(size_t)wn.x << 6];        // coalesced 256B, L2-hot
    const float wv = w * v;
    accm += wv;
    accx = fmaxf(accx, wv);
  }
  out[(size_t)row * 128 + lane]      = accm * (1.f / K_NN);
  out[(size_t)row * 128 + 64 + lane] = accx;
}

// ---------------------------------------------------------------------------
extern "C" void kernel_launch(void* const* d_in, const int* in_sizes, int n_in,
                              void* d_out, int out_size, void* d_ws, size_t ws_size,
                              hipStream_t stream) {
  const float* x  = (const float*)d_in[0];
  const float* Ws = (const float*)d_in[1];
  const float* bs = (const float*)d_in[2];
  const float* Wp = (const float*)d_in[3];
  const float* bp = (const float*)d_in[4];
  float* out = (float*)d_out;

  // workspace layout: prop [N,64] f32 (4 MB) | space [N,4] f32 (256 KB)
  float* prop  = (float*)d_ws;
  float* space = (float*)((char*)d_ws + (size_t)N_TOT * PROP_D * sizeof(float));

  linear_kernel<<<N_TOT / 64, 256, 0, stream>>>(x, Ws, bs, Wp, bp, space, prop);
  knn_kernel<<<N_TOT / 8, 512, 0, stream>>>((const float4*)space, prop, out);
}

// Round 19
// 51.699 us; speedup vs baseline: 4.0523x; 1.0112x over previous
//
#include <hip/hip_runtime.h>
#include <hip/hip_bf16.h>
#include <math.h>

#define N_TOT   16384
#define M_EV    4096
#define IN_DIM  128
#define SPACE_D 4
#define PROP_D  64
#define K_NN    32
#define CAND_CAP 128            // survivor slots per row (2/lane)
#define MARGIN  0.04f           // covers f16 approx error near threshold (>= 2*err)

typedef _Float16 h2 __attribute__((ext_vector_type(2)));
typedef __attribute__((ext_vector_type(8))) _Float16 h16x8;
typedef __attribute__((ext_vector_type(4))) float f32x4;
typedef unsigned long long u64;

__device__ __forceinline__ h2 pkmin(h2 a, h2 b) {
#if __has_builtin(__builtin_elementwise_min)
  return __builtin_elementwise_min(a, b);
#else
  h2 r; r.x = (a.x < b.x) ? a.x : b.x; r.y = (a.y < b.y) ? a.y : b.y; return r;
#endif
}

__device__ __forceinline__ h2 pkrtz(float a, float b) {
  return __builtin_bit_cast(h2, __builtin_amdgcn_cvt_pkrtz(a, b));
}

// per-lane count of set bits of mk strictly below this lane
__device__ __forceinline__ int mbcnt64(u64 mk) {
  return (int)__builtin_amdgcn_mbcnt_hi((unsigned)(mk >> 32),
           __builtin_amdgcn_mbcnt_lo((unsigned)mk, 0u));
}

// ---------------------------------------------------------------------------
// Kernel 1: space = x @ Ws + bs (exact f32) + packed-f16 spaceh (pair-adjacent
// layout: pair p holds rows 2p,2p+1 as u16[8] = [x0,x1,y0,y1,z0,z1,w0,w1]);
// prop = x @ Wp + bp via mfma_f32_16x16x32_f16 (f32 accumulate).
// Grid 1024 x 256 thr (4 blocks/CU = 16 waves/CU): block = one 16-row tile,
// wave = one 16-col tile (4 MFMAs; B-fragments from L1-resident Wp, no LDS).
// Space path: 16 lanes/wave, 4 rows/wave. pkrtz rounding matches old stage.
// ---------------------------------------------------------------------------
__global__ __launch_bounds__(256) void linear_kernel(
    const float* __restrict__ x,
    const float* __restrict__ Ws, const float* __restrict__ bs,
    const float* __restrict__ Wp, const float* __restrict__ bp,
    float* __restrict__ space, unsigned short* __restrict__ spaceh,
    float* __restrict__ prop)
{
  const int lane = threadIdx.x & 63;
  const int wid  = threadIdx.x >> 6;                   // 0..3
  const int r0w  = (int)blockIdx.x * 16;               // block's 16-row tile
  const int arow = lane & 15;

  // ---- space: wave wid covers rows wid*4 .. wid*4+3; 16 active lanes ----
  if ((lane & 15) < 4) {
    const int r = (wid << 2) + (lane >> 4);            // 0..15
    const int c = lane & 3;
    const int gr = r0w + r;
    const float4* __restrict__ xq = (const float4*)(x + (size_t)gr * IN_DIM);
    float a = bs[c];
    #pragma unroll
    for (int i = 0; i < 32; ++i) {
      const float4 v = xq[i];
      a = fmaf(v.x, Ws[(i * 4 + 0) * SPACE_D + c], a);
      a = fmaf(v.y, Ws[(i * 4 + 1) * SPACE_D + c], a);
      a = fmaf(v.z, Ws[(i * 4 + 2) * SPACE_D + c], a);
      a = fmaf(v.w, Ws[(i * 4 + 3) * SPACE_D + c], a);
    }
    space[(size_t)gr * SPACE_D + c] = a;
    // packed f16 (RTZ, identical to old knn stage rounding)
    const unsigned short hb =
        (unsigned short)__builtin_bit_cast(unsigned, pkrtz(a, a));
    spaceh[((size_t)(gr >> 1) << 3) + (c << 1) + (gr & 1)] = hb;
  }

  // ---- prop: wave wid computes col-tile wid (16 cols), 4 k-steps ----
  f32x4 acc = {0.f, 0.f, 0.f, 0.f};
  const int kgrp = (lane >> 4) * 8;                    // k-group base
  const int col  = (wid << 4) + arow;                  // output col

  #pragma unroll
  for (int kk = 0; kk < 4; ++kk) {
    const int kb = kk * 32 + kgrp;
    // A fragment: x[r0w+arow][kb..kb+8)
    const float4* xa = (const float4*)(x + (size_t)(r0w + arow) * IN_DIM + kb);
    const float4 a0 = xa[0], a1 = xa[1];
    uint4 au;
    au.x = __builtin_bit_cast(unsigned, pkrtz(a0.x, a0.y));
    au.y = __builtin_bit_cast(unsigned, pkrtz(a0.z, a0.w));
    au.z = __builtin_bit_cast(unsigned, pkrtz(a1.x, a1.y));
    au.w = __builtin_bit_cast(unsigned, pkrtz(a1.z, a1.w));
    const h16x8 afrag = __builtin_bit_cast(h16x8, au);

    // B fragment: Wp[kb..kb+8)[col] straight from global (L1/L2-hot)
    const float w0 = Wp[(kb + 0) * PROP_D + col];
    const float w1 = Wp[(kb + 1) * PROP_D + col];
    const float w2 = Wp[(kb + 2) * PROP_D + col];
    const float w3 = Wp[(kb + 3) * PROP_D + col];
    const float w4 = Wp[(kb + 4) * PROP_D + col];
    const float w5 = Wp[(kb + 5) * PROP_D + col];
    const float w6 = Wp[(kb + 6) * PROP_D + col];
    const float w7 = Wp[(kb + 7) * PROP_D + col];
    uint4 bu;
    bu.x = __builtin_bit_cast(unsigned, pkrtz(w0, w1));
    bu.y = __builtin_bit_cast(unsigned, pkrtz(w2, w3));
    bu.z = __builtin_bit_cast(unsigned, pkrtz(w4, w5));
    bu.w = __builtin_bit_cast(unsigned, pkrtz(w6, w7));
    const h16x8 bfrag = __builtin_bit_cast(h16x8, bu);

    acc = __builtin_amdgcn_mfma_f32_16x16x32_f16(afrag, bfrag, acc, 0, 0, 0);
  }

  // store: C/D col = lane&15 (-> our 'col'), row = (lane>>4)*4 + j
  {
    const int rbase = (lane >> 4) * 4;
    const float bpc = bp[col];
    #pragma unroll
    for (int j = 0; j < 4; ++j)
      prop[(size_t)(r0w + rbase + j) * PROP_D + col] = acc[j] + bpc;
  }
}

// ---------------------------------------------------------------------------
// Kernel 2: per-row exact KNN (K=32 of 4096) + weighted aggregation.
// R15/R18 structure (measured best). Stage is now a pure 16B copy of the
// pre-packed spaceh (pair-adjacent: s_pk[p] = rows {2p, 2p+1}); survivor
// indices become 2p / 2p+1. All else identical to the verified R18 kernel.
// ---------------------------------------------------------------------------
__global__ __launch_bounds__(512, 3) void knn_kernel(
    const float4* __restrict__ space,     // [N_TOT] f32 coords
    const uint4*  __restrict__ spaceh,    // [N_TOT/2] packed f16 pairs
    const float*  __restrict__ prop,      // [N_TOT * PROP_D]
    float*        __restrict__ out)       // [N_TOT * 2*PROP_D]
{
  const int lane = threadIdx.x & 63;
  const int wid  = threadIdx.x >> 6;              // 0..7
  const int row  = (int)blockIdx.x * 8 + wid;     // 1 wave = 1 row
  const int m0   = row & ~(M_EV - 1);
  const int mloc = row & (M_EV - 1);

  __shared__ uint4 s_pk[M_EV / 2];                // 32 KB pair-packed f16
  __shared__ int   s_ci[8][CAND_CAP];             // 4 KB survivor indices
  __shared__ uint2 s_w[8][K_NN];                  // 2 KB winners {idx, wbits}
  __shared__ int   s_cnt[8];

  // stage: pure copy of pre-packed pairs (no cvt, half the read bytes)
  {
    const uint4* src = spaceh + (size_t)(m0 >> 1);
    #pragma unroll
    for (int it = 0; it < 4; ++it) {
      const int i = (int)threadIdx.x + it * 512;
      s_pk[i] = src[i];
    }
  }
  if (lane == 0) s_cnt[wid] = 0;
  __syncthreads();

  // query coords: exact f32 (for refine) + duplicated f16 packs
  const float4 qf = space[m0 + mloc];
  const h2 qx = pkrtz(qf.x, qf.x), qy = pkrtz(qf.y, qf.y);
  const h2 qz = pkrtz(qf.z, qf.z), qw = pkrtz(qf.w, qf.w);

  // --- pass A: packed distances -> 32 regs + running packed min ---
  unsigned pd[32];
  h2 mn; mn.x = (_Float16)65504.f; mn.y = (_Float16)65504.f;
  #pragma unroll
  for (int t = 0; t < 32; ++t) {
    const uint4 u = s_pk[lane + (t << 6)];
    const h2 dx = qx - __builtin_bit_cast(h2, u.x);
    const h2 dy = qy - __builtin_bit_cast(h2, u.y);
    const h2 dz = qz - __builtin_bit_cast(h2, u.z);
    const h2 dw = qw - __builtin_bit_cast(h2, u.w);
    h2 s = dx * dx;
    s = dy * dy + s;
    s = dz * dz + s;
    s = dw * dw + s;
    pd[t] = __builtin_bit_cast(unsigned, s);
    mn = pkmin(mn, s);
  }

  // --- Tub: 32nd smallest of 128 partition mins, bisect on f16 CODE space ---
  const unsigned mnbits = __builtin_bit_cast(unsigned, mn);
  const unsigned c0 = mnbits & 0xFFFFu, c1 = mnbits >> 16;
  unsigned blo = 0u, bhi = 0x7C00u;
  while (blo < bhi) {
    const unsigned mid = (blo + bhi) >> 1;
    const int c = (int)__popcll(__ballot(c0 <= mid)) +
                  (int)__popcll(__ballot(c1 <= mid));
    if (c >= K_NN) { bhi = mid; if (c == K_NN) break; }
    else blo = mid + 1;
  }
  const float T = (float)__builtin_bit_cast(_Float16, (unsigned short)bhi) + MARGIN;
  const h2 Th = pkrtz(T, T);                      // RTZ error << MARGIN

  // --- pass B: compares + LDS-atomic append of indices (cands 2p, 2p+1) ---
  #pragma unroll
  for (int t = 0; t < 32; ++t) {
    const h2 s = __builtin_bit_cast(h2, pd[t]);
    const int p2 = ((t << 6) + lane) << 1;
    if (s.x <= Th.x) {
      const int pos = atomicAdd(&s_cnt[wid], 1);
      if (pos < CAND_CAP) s_ci[wid][pos] = p2;
    }
    if (s.y <= Th.y) {
      const int pos = atomicAdd(&s_cnt[wid], 1);
      if (pos < CAND_CAP) s_ci[wid][pos] = p2 + 1;
    }
  }
  int C = s_cnt[wid];

  if (C > CAND_CAP) {
    // --- cold exact fallback: bisect exact f32 d from global, fill top-32 ---
    const float4* __restrict__ ev = space + m0;
    unsigned lo = 0u, hi = __float_as_uint(T);
    while (lo < hi) {
      const unsigned mid = (lo + hi) >> 1;
      const float fm = __uint_as_float(mid);
      int c = 0;
      #pragma unroll 1
      for (int t = 0; t < 64; ++t) {
        const float4 cc = ev[lane + (t << 6)];
        const float dx = qf.x - cc.x, dy = qf.y - cc.y;
        const float dz = qf.z - cc.z, dw = qf.w - cc.w;
        const float dd = fmaf(dx, dx, fmaf(dy, dy, fmaf(dz, dz, dw * dw)));
        c += (int)__popcll(__ballot(dd <= fm));
      }
      if (c >= K_NN) { hi = mid; if (c == K_NN) break; }
      else lo = mid + 1;
    }
    const float Tf = __uint_as_float(hi);
    int cnt = 0;
    #pragma unroll 1
    for (int pass = 0; pass < 2; ++pass) {        // 0: strict-less, 1: equal
      #pragma unroll 1
      for (int t = 0; t < 64; ++t) {
        const float4 cc = ev[lane + (t << 6)];
        const float dx = qf.x - cc.x, dy = qf.y - cc.y;
        const float dz = qf.z - cc.z, dw = qf.w - cc.w;
        const float dd = fmaf(dx, dx, fmaf(dy, dy, fmaf(dz, dz, dw * dw)));
        const bool p = pass ? (dd == Tf) : (dd < Tf);
        const u64 mk = __ballot(p);
        if (p) {
          const int pos = cnt + mbcnt64(mk);
          if (pos < K_NN) s_ci[wid][pos] = (t << 6) + lane;
        }
        cnt += (int)__popcll(mk);
      }
      if (cnt >= K_NN) break;
    }
    C = K_NN;
  }

  // --- refine: exact f32 distances for <=2 survivors/lane (global, L2) ---
  const bool h0 = (lane < C), h1 = (64 + lane < C);
  const int i0 = h0 ? s_ci[wid][lane]      : 0;
  const int i1 = h1 ? s_ci[wid][64 + lane] : 0;
  float v0 = INFINITY, v1 = INFINITY;
  if (h0) {
    const float4 cc = space[m0 + i0];
    const float dx = qf.x - cc.x, dy = qf.y - cc.y;
    const float dz = qf.z - cc.z, dw = qf.w - cc.w;
    v0 = fmaf(dx, dx, fmaf(dy, dy, fmaf(dz, dz, dw * dw)));
  }
  if (h1) {
    const float4 cc = space[m0 + i1];
    const float dx = qf.x - cc.x, dy = qf.y - cc.y;
    const float dz = qf.z - cc.z, dw = qf.w - cc.w;
    v1 = fmaf(dx, dx, fmaf(dy, dy, fmaf(dz, dz, dw * dw)));
  }

  // --- tail: f32-bits bisect (early exit at c==32) on <=2 values/lane ---
  unsigned lo = 0u, hi = __float_as_uint(T);
  while (lo < hi) {
    const unsigned mid = (lo + hi) >> 1;
    const float fm = __uint_as_float(mid);
    const int c = (int)__popcll(__ballot(v0 <= fm)) +
                  (int)__popcll(__ballot(v1 <= fm));
    if (c >= K_NN) { hi = mid; if (c == K_NN) break; }
    else lo = mid + 1;
  }
  const float T2 = __uint_as_float(hi);

  // stable selection: strict-less, then lowest-position equals (JAX order)
  const u64 mkE0 = __ballot(v0 == T2);
  const u64 mkE1 = __ballot(v1 == T2);
  const int L = (int)__popcll(__ballot(v0 < T2)) +
                (int)__popcll(__ballot(v1 < T2));
  const int e = K_NN - L;
  const int nE0 = (int)__popcll(mkE0);
  const bool sel0 = (v0 < T2) || ((v0 == T2) && (mbcnt64(mkE0) < e));
  const bool sel1 = (v1 < T2) || ((v1 == T2) && (nE0 + mbcnt64(mkE1) < e));

  const float w0 = __expf(-10.f * v0);
  const float w1 = __expf(-10.f * v1);

  {
    const u64 mkS0 = __ballot(sel0);
    if (sel0) {
      const int pos = mbcnt64(mkS0);
      s_w[wid][pos] = make_uint2((unsigned)i0, __float_as_uint(w0));
    }
    const int b0 = (int)__popcll(mkS0);
    const u64 mkS1 = __ballot(sel1);
    if (sel1) {
      const int pos = b0 + mbcnt64(mkS1);
      s_w[wid][pos] = make_uint2((unsigned)i1, __float_as_uint(w1));
    }
  }

  // --- aggregation: lane = feature, 32 winners ---
  float accm = 0.f;
  float accx = -INFINITY;
  const float* __restrict__ pb = prop + ((size_t)m0 << 6) + lane;
  #pragma unroll 8
  for (int n = 0; n < K_NN; ++n) {
    const uint2 wn = s_w[wid][n];                 // uniform LDS broadcast
    const float w = __uint_as_float(wn.y);
    const float v = pb[(size_t)wn.x << 6];        // coalesced 256B, L2-hot
    const float wv = w * v;
    accm += wv;
    accx = fmaxf(accx, wv);
  }
  out[(size_t)row * 128 + lane]      = accm * (1.f / K_NN);
  out[(size_t)row * 128 + 64 + lane] = accx;
}

// ---------------------------------------------------------------------------
extern "C" void kernel_launch(void* const* d_in, const int* in_sizes, int n_in,
                              void* d_out, int out_size, void* d_ws, size_t ws_size,
                              hipStream_t stream) {
  const float* x  = (const float*)d_in[0];
  const float* Ws = (const float*)d_in[1];
  const float* bs = (const float*)d_in[2];
  const float* Wp = (const float*)d_in[3];
  const float* bp = (const float*)d_in[4];
  float* out = (float*)d_out;

  // workspace: prop [N,64] f32 (4 MB) | space [N,4] f32 (256 KB)
  //            | spaceh [N/2] uint4 packed f16 pairs (128 KB)
  float* prop  = (float*)d_ws;
  float* space = (float*)((char*)d_ws + (size_t)N_TOT * PROP_D * sizeof(float));
  unsigned short* spaceh = (unsigned short*)((char*)space
                           + (size_t)N_TOT * SPACE_D * sizeof(float));

  linear_kernel<<<N_TOT / 16, 256, 0, stream>>>(x, Ws, bs, Wp, bp,
                                                space, spaceh, prop);
  knn_kernel<<<N_TOT / 8, 512, 0, stream>>>((const float4*)space,
                                            (const uint4*)spaceh, prop, out);
}